// Round 2
// baseline (863.994 us; speedup 1.0000x reference)
//
#include <hip/hip_runtime.h>
#include <hip/hip_bf16.h>

// GCN 2-layer, N=100000 nodes, D=512 -> 16 -> 7, E=3.2M edges (+ implicit self loops).
// Strategy: build CSR-by-dst once (hist + scan + scatter), reuse for both layers.
// Self-loop message (dinv^2 * h[i] + b) fused into GEMM epilogues.

#define N_NODES 100000
#define NPAD    100352   // 98 * 1024, padded for int4/block-scan convenience
#define NSCB    98       // scan blocks (1024 elems each)
#define D_IN    512
#define H1DIM   16
#define C_OUT   7
#define C_PAD   8

// ---------------- CSR build ----------------

__global__ __launch_bounds__(256) void k_zero_counts(int* __restrict__ count) {
    int i = blockIdx.x * 256 + threadIdx.x;
    if (i < NPAD) count[i] = 0;
}

__global__ __launch_bounds__(256) void k_hist(const int* __restrict__ dst, int E,
                                              int* __restrict__ count) {
    int e = blockIdx.x * 256 + threadIdx.x;
    if (e < E) atomicAdd(&count[dst[e]], 1);
}

// per-block (1024 elems) sum of counts; also dinv = rsqrt(count + 1 self loop)
__global__ __launch_bounds__(256) void k_blocksum(const int4* __restrict__ count4,
                                                  float4* __restrict__ dinv4,
                                                  int* __restrict__ bsum) {
    __shared__ int sm[256];
    int b = blockIdx.x, tid = threadIdx.x;
    int idx = b * 256 + tid;               // int4 index, covers NPAD/4
    int4 v = count4[idx];
    float4 dv;
    dv.x = rsqrtf(1.0f + (float)v.x);
    dv.y = rsqrtf(1.0f + (float)v.y);
    dv.z = rsqrtf(1.0f + (float)v.z);
    dv.w = rsqrtf(1.0f + (float)v.w);
    dinv4[idx] = dv;
    sm[tid] = v.x + v.y + v.z + v.w;
    __syncthreads();
    for (int off = 128; off > 0; off >>= 1) {
        if (tid < off) sm[tid] += sm[tid + off];
        __syncthreads();
    }
    if (tid == 0) bsum[b] = sm[0];
}

__global__ void k_scan_sums(const int* __restrict__ bsum, int* __restrict__ bprefix) {
    if (blockIdx.x == 0 && threadIdx.x == 0) {
        int r = 0;
        for (int i = 0; i < NSCB; ++i) { bprefix[i] = r; r += bsum[i]; }
    }
}

__global__ __launch_bounds__(256) void k_scan_block(const int4* __restrict__ count4,
                                                    const int* __restrict__ bprefix,
                                                    int4* __restrict__ offs4,
                                                    int4* __restrict__ wptr4) {
    __shared__ int sm[256];
    int b = blockIdx.x, tid = threadIdx.x;
    int idx = b * 256 + tid;
    int4 v = count4[idx];
    int tsum = v.x + v.y + v.z + v.w;
    sm[tid] = tsum;
    __syncthreads();
    for (int off = 1; off < 256; off <<= 1) {
        int add = (tid >= off) ? sm[tid - off] : 0;
        __syncthreads();
        sm[tid] += add;
        __syncthreads();
    }
    int excl = sm[tid] - tsum;               // exclusive prefix of thread sums
    int base = bprefix[b] + excl;
    int4 o;
    o.x = base;
    o.y = o.x + v.x;
    o.z = o.y + v.y;
    o.w = o.z + v.z;
    offs4[idx] = o;
    wptr4[idx] = o;
}

__global__ __launch_bounds__(256) void k_scatter(const int* __restrict__ src,
                                                 const int* __restrict__ dst, int E,
                                                 int* __restrict__ wptr,
                                                 int* __restrict__ sorted_src) {
    int e = blockIdx.x * 256 + threadIdx.x;
    if (e < E) {
        int d = dst[e];
        int pos = atomicAdd(&wptr[d], 1);
        sorted_src[pos] = src[e];
    }
}

// ---------------- layer math ----------------

// h1 = x @ W1 ; out1 = dinv^2 * h1 + b1   (self-loop message + bias fused)
__global__ __launch_bounds__(128) void k_gemm1(const float* __restrict__ x,
                                               const float* __restrict__ W1,
                                               const float* __restrict__ b1,
                                               const float* __restrict__ dinv,
                                               float* __restrict__ h1,
                                               float* __restrict__ out1) {
    int row = blockIdx.x * 128 + threadIdx.x;
    if (row >= N_NODES) return;
    const float4* x4 = (const float4*)(x + (size_t)row * D_IN);
    const float4* W14 = (const float4*)W1;   // W1 row d = 4 float4 at d*4
    float acc[16];
#pragma unroll
    for (int k = 0; k < 16; ++k) acc[k] = 0.0f;

#pragma unroll 4
    for (int d4 = 0; d4 < D_IN / 4; ++d4) {
        float4 xv = x4[d4];
#pragma unroll
        for (int r = 0; r < 4; ++r) {
            int d = d4 * 4 + r;
            float xs = (r == 0) ? xv.x : (r == 1) ? xv.y : (r == 2) ? xv.z : xv.w;
#pragma unroll
            for (int q = 0; q < 4; ++q) {
                float4 w = W14[d * 4 + q];      // wave-uniform address
                acc[q * 4 + 0] = fmaf(xs, w.x, acc[q * 4 + 0]);
                acc[q * 4 + 1] = fmaf(xs, w.y, acc[q * 4 + 1]);
                acc[q * 4 + 2] = fmaf(xs, w.z, acc[q * 4 + 2]);
                acc[q * 4 + 3] = fmaf(xs, w.w, acc[q * 4 + 3]);
            }
        }
    }

    float di = dinv[row];
    float di2 = di * di;
    float4* h14 = (float4*)(h1 + (size_t)row * H1DIM);
    float4* o14 = (float4*)(out1 + (size_t)row * H1DIM);
    const float4* b14 = (const float4*)b1;
#pragma unroll
    for (int q = 0; q < 4; ++q) {
        float4 a;
        a.x = acc[q * 4 + 0]; a.y = acc[q * 4 + 1];
        a.z = acc[q * 4 + 2]; a.w = acc[q * 4 + 3];
        h14[q] = a;
        float4 bq = b14[q];
        float4 o;
        o.x = fmaf(di2, a.x, bq.x);
        o.y = fmaf(di2, a.y, bq.y);
        o.z = fmaf(di2, a.z, bq.z);
        o.w = fmaf(di2, a.w, bq.w);
        o14[q] = o;
    }
}

// one wave per node: out1[node] += sum_e dinv[src]*dinv[node] * h1[src]
__global__ __launch_bounds__(256) void k_msg1(const int* __restrict__ offs,
                                              const int* __restrict__ count,
                                              const int* __restrict__ sorted_src,
                                              const float* __restrict__ dinv,
                                              const float* __restrict__ h1,
                                              float* __restrict__ out1) {
    int node = blockIdx.x * 4 + (threadIdx.x >> 6);
    if (node >= N_NODES) return;
    int lane = threadIdx.x & 63;
    int s = lane >> 4;       // edge slot 0..3
    int k = lane & 15;       // feature
    int off = offs[node];
    int cnt = count[node];
    float dvi = dinv[node];
    float acc = 0.0f;
    for (int c = s; c < cnt; c += 4) {
        int sv = sorted_src[off + c];
        float w = dinv[sv] * dvi;
        acc = fmaf(w, h1[(size_t)sv * H1DIM + k], acc);
    }
    acc += __shfl_xor(acc, 16);
    acc += __shfl_xor(acc, 32);
    if (s == 0) out1[(size_t)node * H1DIM + k] += acc;
}

// h2 = relu(out1) @ W2 ; out2 = dinv^2*h2 + b2 (padded stride 8)
__global__ __launch_bounds__(256) void k_gemm2(const float* __restrict__ out1,
                                               const float* __restrict__ W2,
                                               const float* __restrict__ b2,
                                               const float* __restrict__ dinv,
                                               float* __restrict__ h2,
                                               float* __restrict__ out2) {
    int i = blockIdx.x * 256 + threadIdx.x;
    if (i >= N_NODES) return;
    const float4* o14 = (const float4*)(out1 + (size_t)i * H1DIM);
    float v[16];
#pragma unroll
    for (int q = 0; q < 4; ++q) {
        float4 a = o14[q];
        v[q * 4 + 0] = fmaxf(a.x, 0.0f);
        v[q * 4 + 1] = fmaxf(a.y, 0.0f);
        v[q * 4 + 2] = fmaxf(a.z, 0.0f);
        v[q * 4 + 3] = fmaxf(a.w, 0.0f);
    }
    float h[7];
#pragma unroll
    for (int j = 0; j < 7; ++j) h[j] = 0.0f;
#pragma unroll
    for (int k = 0; k < 16; ++k) {
#pragma unroll
        for (int j = 0; j < 7; ++j) h[j] = fmaf(v[k], W2[k * 7 + j], h[j]);
    }
    float di = dinv[i];
    float di2 = di * di;
    float* h2r = h2 + (size_t)i * C_PAD;
    float* o2r = out2 + (size_t)i * C_PAD;
#pragma unroll
    for (int j = 0; j < 7; ++j) {
        h2r[j] = h[j];
        o2r[j] = fmaf(di2, h[j], b2[j]);
    }
    h2r[7] = 0.0f;
    o2r[7] = 0.0f;
}

// one wave per node, 8 edge slots x 8 features (feature 7 is the zero pad)
__global__ __launch_bounds__(256) void k_msg2(const int* __restrict__ offs,
                                              const int* __restrict__ count,
                                              const int* __restrict__ sorted_src,
                                              const float* __restrict__ dinv,
                                              const float* __restrict__ h2,
                                              float* __restrict__ out2) {
    int node = blockIdx.x * 4 + (threadIdx.x >> 6);
    if (node >= N_NODES) return;
    int lane = threadIdx.x & 63;
    int s = lane >> 3;       // edge slot 0..7
    int j = lane & 7;        // feature (7 = pad)
    int off = offs[node];
    int cnt = count[node];
    float dvi = dinv[node];
    float acc = 0.0f;
    for (int c = s; c < cnt; c += 8) {
        int sv = sorted_src[off + c];
        float w = dinv[sv] * dvi;
        acc = fmaf(w, h2[(size_t)sv * C_PAD + j], acc);
    }
    acc += __shfl_xor(acc, 8);
    acc += __shfl_xor(acc, 16);
    acc += __shfl_xor(acc, 32);
    if (s == 0) out2[(size_t)node * C_PAD + j] += acc;
}

__global__ __launch_bounds__(256) void k_logsm(const float* __restrict__ out2,
                                               float* __restrict__ out) {
    int i = blockIdx.x * 256 + threadIdx.x;
    if (i >= N_NODES) return;
    const float* r = out2 + (size_t)i * C_PAD;
    float v[7];
#pragma unroll
    for (int j = 0; j < 7; ++j) v[j] = r[j];
    float m = v[0];
#pragma unroll
    for (int j = 1; j < 7; ++j) m = fmaxf(m, v[j]);
    float ssum = 0.0f;
#pragma unroll
    for (int j = 0; j < 7; ++j) ssum += expf(v[j] - m);
    float l = logf(ssum);
    float* o = out + (size_t)i * C_OUT;
#pragma unroll
    for (int j = 0; j < 7; ++j) o[j] = v[j] - m - l;
}

// ---------------- launch ----------------

extern "C" void kernel_launch(void* const* d_in, const int* in_sizes, int n_in,
                              void* d_out, int out_size, void* d_ws, size_t ws_size,
                              hipStream_t stream) {
    const float* x  = (const float*)d_in[0];
    const int*   ei = (const int*)d_in[1];
    const float* W1 = (const float*)d_in[2];
    const float* b1 = (const float*)d_in[3];
    const float* W2 = (const float*)d_in[4];
    const float* b2 = (const float*)d_in[5];
    float* out = (float*)d_out;

    const int E = in_sizes[1] / 2;
    const int* src = ei;
    const int* dst = ei + E;

    // workspace carve-up (256B aligned)
    char* w = (char*)d_ws;
    size_t off = 0;
    auto alloc = [&](size_t bytes) -> void* {
        off = (off + 255) & ~(size_t)255;
        void* p = w + off;
        off += bytes;
        return p;
    };
    int*   count      = (int*)alloc(NPAD * 4);
    int*   offs       = (int*)alloc(NPAD * 4);
    int*   wptr       = (int*)alloc(NPAD * 4);
    float* dinv       = (float*)alloc(NPAD * 4);
    int*   bsum       = (int*)alloc(NSCB * 4);
    int*   bprefix    = (int*)alloc(NSCB * 4);
    int*   sorted_src = (int*)alloc((size_t)E * 4);
    float* h1   = (float*)alloc((size_t)N_NODES * H1DIM * 4);
    float* out1 = (float*)alloc((size_t)N_NODES * H1DIM * 4);
    float* h2   = (float*)alloc((size_t)N_NODES * C_PAD * 4);
    float* out2 = (float*)alloc((size_t)N_NODES * C_PAD * 4);
    (void)ws_size; // total ~33.3 MB

    const int gE = (E + 255) / 256;
    const int gN4 = (N_NODES + 3) / 4;          // msg kernels: 4 nodes/block
    const int gN256 = (N_NODES + 255) / 256;

    k_zero_counts<<<NPAD / 256, 256, 0, stream>>>(count);
    k_hist<<<gE, 256, 0, stream>>>(dst, E, count);
    k_blocksum<<<NSCB, 256, 0, stream>>>((const int4*)count, (float4*)dinv, bsum);
    k_scan_sums<<<1, 64, 0, stream>>>(bsum, bprefix);
    k_scan_block<<<NSCB, 256, 0, stream>>>((const int4*)count, bprefix,
                                           (int4*)offs, (int4*)wptr);
    k_scatter<<<gE, 256, 0, stream>>>(src, dst, E, wptr, sorted_src);

    k_gemm1<<<(N_NODES + 127) / 128, 128, 0, stream>>>(x, W1, b1, dinv, h1, out1);
    k_msg1<<<gN4, 256, 0, stream>>>(offs, count, sorted_src, dinv, h1, out1);
    k_gemm2<<<gN256, 256, 0, stream>>>(out1, W2, b2, dinv, h2, out2);
    k_msg2<<<gN4, 256, 0, stream>>>(offs, count, sorted_src, dinv, h2, out2);
    k_logsm<<<gN256, 256, 0, stream>>>(out2, out);
}

// Round 3
// 540.423 us; speedup vs baseline: 1.5987x; 1.5987x over previous
//
#include <hip/hip_runtime.h>
#include <hip/hip_bf16.h>

// GCN 2-layer, N=100000 nodes, D=512 -> 16 -> 7, E=3.2M edges (+ implicit self loops).
// Round 3: CSR build via radix partition (bucket by dst/196, LDS counting sort per
// bucket) — replaces the 270us random-scatter (194MB write amplification) and the
// 3.2M-atomic global histogram. Self-loop message fused into GEMM epilogues.

#define N_NODES 100000
#define NPAD    100352   // 512 * 196
#define D_IN    512
#define H1DIM   16
#define C_OUT   7
#define C_PAD   8

#define NB      196      // nodes per bucket
#define NBUCK   512      // buckets (NBUCK*NB = 100352 >= N)
#define BCAP    8192     // per-bucket entry capacity in pass B (mean 6250, +24 sigma)
#define TILE_A  8192     // edges per pass-A workgroup (512 thr x 16)

// ---------------- CSR build ----------------

__global__ __launch_bounds__(256) void k_zinit(int* __restrict__ bcount) {
    int i = blockIdx.x * 256 + threadIdx.x;
    if (i < NBUCK) bcount[i] = 0;
}

// coarse histogram of dst buckets (LDS-accumulated)
__global__ __launch_bounds__(256) void k_bhist(const int* __restrict__ dst, int E,
                                               int* __restrict__ bcount) {
    __shared__ int h[NBUCK];
    for (int i = threadIdx.x; i < NBUCK; i += 256) h[i] = 0;
    __syncthreads();
    int stride = gridDim.x * 256;
    for (int e = blockIdx.x * 256 + threadIdx.x; e < E; e += stride)
        atomicAdd(&h[(unsigned)dst[e] / NB], 1);
    __syncthreads();
    for (int i = threadIdx.x; i < NBUCK; i += 256) {
        int v = h[i];
        if (v) atomicAdd(&bcount[i], v);
    }
}

// single-WG scan of 512 bucket counts -> bases + write cursors
__global__ void k_bscan(const int* __restrict__ bcount, int* __restrict__ bbase,
                        int* __restrict__ cursor) {
    __shared__ int sm[NBUCK];
    int t = threadIdx.x;                 // 512 threads
    int c = bcount[t];
    sm[t] = c;
    __syncthreads();
    for (int off = 1; off < NBUCK; off <<= 1) {
        int v = (t >= off) ? sm[t - off] : 0;
        __syncthreads();
        sm[t] += v;
        __syncthreads();
    }
    int excl = sm[t] - c;
    bbase[t] = excl;
    cursor[t] = excl;
    if (t == NBUCK - 1) bbase[NBUCK] = sm[t];
}

// partition edges into dst buckets; payload packs (dst_local<<17 | src)
__global__ __launch_bounds__(512) void k_passA(const int* __restrict__ src,
                                               const int* __restrict__ dst, int E,
                                               int* __restrict__ cursor,
                                               unsigned* __restrict__ packed) {
    __shared__ int hist[NBUCK];
    __shared__ int wp[NBUCK];
    int tile0 = blockIdx.x * TILE_A;
    for (int i = threadIdx.x; i < NBUCK; i += 512) hist[i] = 0;
    __syncthreads();
    unsigned pay[16];
    unsigned short bk[16];
#pragma unroll
    for (int r = 0; r < 16; ++r) {
        int e = tile0 + r * 512 + threadIdx.x;
        if (e < E) {
            unsigned d = (unsigned)dst[e];
            unsigned s = (unsigned)src[e];
            unsigned b = d / NB;
            pay[r] = ((d - b * NB) << 17) | s;
            bk[r] = (unsigned short)b;
            atomicAdd(&hist[b], 1);
        } else {
            bk[r] = 0xffffu;
        }
    }
    __syncthreads();
    if (threadIdx.x < NBUCK) {
        int c = hist[threadIdx.x];
        wp[threadIdx.x] = (c > 0) ? atomicAdd(&cursor[threadIdx.x], c) : 0;
    }
    __syncthreads();
#pragma unroll
    for (int r = 0; r < 16; ++r) {
        if (bk[r] != 0xffffu) {
            int pos = atomicAdd(&wp[bk[r]], 1);
            packed[pos] = pay[r];
        }
    }
}

// one WG per bucket: LDS counting sort by dst_local; emit sorted_src (coalesced),
// per-node count/offs/dinv (coalesced). No global per-node atomics anywhere.
__global__ __launch_bounds__(256) void k_passB(const unsigned* __restrict__ packed,
                                               const int* __restrict__ bbase,
                                               int* __restrict__ sorted_src,
                                               int* __restrict__ offs,
                                               int* __restrict__ cnt_out,
                                               float* __restrict__ dinv) {
    __shared__ unsigned ent[BCAP];
    __shared__ int sorted[BCAP];
    __shared__ int hist[NB + 1];
    __shared__ int scan[NB + 1];
    __shared__ int wp[NB];
    int b = blockIdx.x;
    int base = bbase[b];
    int cnt = bbase[b + 1] - base;
    if (cnt > BCAP) cnt = BCAP;          // safety clamp (never hit for bench data)
    for (int i = threadIdx.x; i < cnt; i += 256) ent[i] = packed[base + i];
    for (int i = threadIdx.x; i <= NB; i += 256) hist[i] = 0;
    __syncthreads();
    for (int i = threadIdx.x; i < cnt; i += 256) atomicAdd(&hist[ent[i] >> 17], 1);
    __syncthreads();
    if (threadIdx.x <= NB)
        scan[threadIdx.x] = (threadIdx.x == 0) ? 0 : hist[threadIdx.x - 1];
    __syncthreads();
    for (int off = 1; off < 256; off <<= 1) {   // 8 rounds covers 197 elems
        int v = 0;
        if (threadIdx.x <= NB && threadIdx.x >= off) v = scan[threadIdx.x - off];
        __syncthreads();
        if (threadIdx.x <= NB) scan[threadIdx.x] += v;
        __syncthreads();
    }
    int node0 = b * NB;
    if (threadIdx.x < NB) {
        int node = node0 + threadIdx.x;
        if (node < N_NODES) {
            int h = hist[threadIdx.x];
            cnt_out[node] = h;
            offs[node] = base + scan[threadIdx.x];
            dinv[node] = rsqrtf(1.0f + (float)h);
        }
        wp[threadIdx.x] = scan[threadIdx.x];
    }
    __syncthreads();
    for (int i = threadIdx.x; i < cnt; i += 256) {
        unsigned p = ent[i];
        int dl = (int)(p >> 17);
        int pos = atomicAdd(&wp[dl], 1);
        sorted[pos] = (int)(p & 0x1FFFFu);
    }
    __syncthreads();
    for (int i = threadIdx.x; i < cnt; i += 256) sorted_src[base + i] = sorted[i];
}

// ---------------- layer math ----------------

// h1 = x @ W1 ; out1 = dinv^2 * h1 + b1   (self-loop message + bias fused)
__global__ __launch_bounds__(128) void k_gemm1(const float* __restrict__ x,
                                               const float* __restrict__ W1,
                                               const float* __restrict__ b1,
                                               const float* __restrict__ dinv,
                                               float* __restrict__ h1,
                                               float* __restrict__ out1) {
    int row = blockIdx.x * 128 + threadIdx.x;
    if (row >= N_NODES) return;
    const float4* x4 = (const float4*)(x + (size_t)row * D_IN);
    const float4* W14 = (const float4*)W1;   // W1 row d = 4 float4 at d*4
    float acc[16];
#pragma unroll
    for (int k = 0; k < 16; ++k) acc[k] = 0.0f;

#pragma unroll 4
    for (int d4 = 0; d4 < D_IN / 4; ++d4) {
        float4 xv = x4[d4];
#pragma unroll
        for (int r = 0; r < 4; ++r) {
            int d = d4 * 4 + r;
            float xs = (r == 0) ? xv.x : (r == 1) ? xv.y : (r == 2) ? xv.z : xv.w;
#pragma unroll
            for (int q = 0; q < 4; ++q) {
                float4 w = W14[d * 4 + q];      // wave-uniform address
                acc[q * 4 + 0] = fmaf(xs, w.x, acc[q * 4 + 0]);
                acc[q * 4 + 1] = fmaf(xs, w.y, acc[q * 4 + 1]);
                acc[q * 4 + 2] = fmaf(xs, w.z, acc[q * 4 + 2]);
                acc[q * 4 + 3] = fmaf(xs, w.w, acc[q * 4 + 3]);
            }
        }
    }

    float di = dinv[row];
    float di2 = di * di;
    float4* h14 = (float4*)(h1 + (size_t)row * H1DIM);
    float4* o14 = (float4*)(out1 + (size_t)row * H1DIM);
    const float4* b14 = (const float4*)b1;
#pragma unroll
    for (int q = 0; q < 4; ++q) {
        float4 a;
        a.x = acc[q * 4 + 0]; a.y = acc[q * 4 + 1];
        a.z = acc[q * 4 + 2]; a.w = acc[q * 4 + 3];
        h14[q] = a;
        float4 bq = b14[q];
        float4 o;
        o.x = fmaf(di2, a.x, bq.x);
        o.y = fmaf(di2, a.y, bq.y);
        o.z = fmaf(di2, a.z, bq.z);
        o.w = fmaf(di2, a.w, bq.w);
        o14[q] = o;
    }
}

// one wave per node: out1[node] += sum_e dinv[src]*dinv[node] * h1[src]
__global__ __launch_bounds__(256) void k_msg1(const int* __restrict__ offs,
                                              const int* __restrict__ count,
                                              const int* __restrict__ sorted_src,
                                              const float* __restrict__ dinv,
                                              const float* __restrict__ h1,
                                              float* __restrict__ out1) {
    int node = blockIdx.x * 4 + (threadIdx.x >> 6);
    if (node >= N_NODES) return;
    int lane = threadIdx.x & 63;
    int s = lane >> 4;       // edge slot 0..3
    int k = lane & 15;       // feature
    int off = offs[node];
    int cnt = count[node];
    float dvi = dinv[node];
    float acc = 0.0f;
    for (int c = s; c < cnt; c += 4) {
        int sv = sorted_src[off + c];
        float w = dinv[sv] * dvi;
        acc = fmaf(w, h1[(size_t)sv * H1DIM + k], acc);
    }
    acc += __shfl_xor(acc, 16);
    acc += __shfl_xor(acc, 32);
    if (s == 0) out1[(size_t)node * H1DIM + k] += acc;
}

// h2 = relu(out1) @ W2 ; out2 = dinv^2*h2 + b2 (padded stride 8)
__global__ __launch_bounds__(256) void k_gemm2(const float* __restrict__ out1,
                                               const float* __restrict__ W2,
                                               const float* __restrict__ b2,
                                               const float* __restrict__ dinv,
                                               float* __restrict__ h2,
                                               float* __restrict__ out2) {
    int i = blockIdx.x * 256 + threadIdx.x;
    if (i >= N_NODES) return;
    const float4* o14 = (const float4*)(out1 + (size_t)i * H1DIM);
    float v[16];
#pragma unroll
    for (int q = 0; q < 4; ++q) {
        float4 a = o14[q];
        v[q * 4 + 0] = fmaxf(a.x, 0.0f);
        v[q * 4 + 1] = fmaxf(a.y, 0.0f);
        v[q * 4 + 2] = fmaxf(a.z, 0.0f);
        v[q * 4 + 3] = fmaxf(a.w, 0.0f);
    }
    float h[7];
#pragma unroll
    for (int j = 0; j < 7; ++j) h[j] = 0.0f;
#pragma unroll
    for (int k = 0; k < 16; ++k) {
#pragma unroll
        for (int j = 0; j < 7; ++j) h[j] = fmaf(v[k], W2[k * 7 + j], h[j]);
    }
    float di = dinv[i];
    float di2 = di * di;
    float* h2r = h2 + (size_t)i * C_PAD;
    float* o2r = out2 + (size_t)i * C_PAD;
#pragma unroll
    for (int j = 0; j < 7; ++j) {
        h2r[j] = h[j];
        o2r[j] = fmaf(di2, h[j], b2[j]);
    }
    h2r[7] = 0.0f;
    o2r[7] = 0.0f;
}

// one wave per node, 8 edge slots x 8 features (feature 7 is the zero pad)
__global__ __launch_bounds__(256) void k_msg2(const int* __restrict__ offs,
                                              const int* __restrict__ count,
                                              const int* __restrict__ sorted_src,
                                              const float* __restrict__ dinv,
                                              const float* __restrict__ h2,
                                              float* __restrict__ out2) {
    int node = blockIdx.x * 4 + (threadIdx.x >> 6);
    if (node >= N_NODES) return;
    int lane = threadIdx.x & 63;
    int s = lane >> 3;       // edge slot 0..7
    int j = lane & 7;        // feature (7 = pad)
    int off = offs[node];
    int cnt = count[node];
    float dvi = dinv[node];
    float acc = 0.0f;
    for (int c = s; c < cnt; c += 8) {
        int sv = sorted_src[off + c];
        float w = dinv[sv] * dvi;
        acc = fmaf(w, h2[(size_t)sv * C_PAD + j], acc);
    }
    acc += __shfl_xor(acc, 8);
    acc += __shfl_xor(acc, 16);
    acc += __shfl_xor(acc, 32);
    if (s == 0) out2[(size_t)node * C_PAD + j] += acc;
}

__global__ __launch_bounds__(256) void k_logsm(const float* __restrict__ out2,
                                               float* __restrict__ out) {
    int i = blockIdx.x * 256 + threadIdx.x;
    if (i >= N_NODES) return;
    const float* r = out2 + (size_t)i * C_PAD;
    float v[7];
#pragma unroll
    for (int j = 0; j < 7; ++j) v[j] = r[j];
    float m = v[0];
#pragma unroll
    for (int j = 1; j < 7; ++j) m = fmaxf(m, v[j]);
    float ssum = 0.0f;
#pragma unroll
    for (int j = 0; j < 7; ++j) ssum += expf(v[j] - m);
    float l = logf(ssum);
    float* o = out + (size_t)i * C_OUT;
#pragma unroll
    for (int j = 0; j < 7; ++j) o[j] = v[j] - m - l;
}

// ---------------- launch ----------------

extern "C" void kernel_launch(void* const* d_in, const int* in_sizes, int n_in,
                              void* d_out, int out_size, void* d_ws, size_t ws_size,
                              hipStream_t stream) {
    const float* x  = (const float*)d_in[0];
    const int*   ei = (const int*)d_in[1];
    const float* W1 = (const float*)d_in[2];
    const float* b1 = (const float*)d_in[3];
    const float* W2 = (const float*)d_in[4];
    const float* b2 = (const float*)d_in[5];
    float* out = (float*)d_out;

    const int E = in_sizes[1] / 2;
    const int* src = ei;
    const int* dst = ei + E;

    // workspace carve-up (256B aligned)
    char* w = (char*)d_ws;
    size_t off = 0;
    auto alloc = [&](size_t bytes) -> void* {
        off = (off + 255) & ~(size_t)255;
        void* p = w + off;
        off += bytes;
        return p;
    };
    int*   bcount     = (int*)alloc(NBUCK * 4);
    int*   bbase      = (int*)alloc((NBUCK + 1) * 4);
    int*   cursor     = (int*)alloc(NBUCK * 4);
    int*   count      = (int*)alloc(NPAD * 4);
    int*   offs       = (int*)alloc(NPAD * 4);
    float* dinv       = (float*)alloc(NPAD * 4);
    int*   sorted_src = (int*)alloc((size_t)E * 4);
    float* h1   = (float*)alloc((size_t)N_NODES * H1DIM * 4);   // 6.4 MB
    float* out1 = (float*)alloc((size_t)N_NODES * H1DIM * 4);   // 6.4 MB
    float* h2   = (float*)alloc((size_t)N_NODES * C_PAD * 4);
    float* out2 = (float*)alloc((size_t)N_NODES * C_PAD * 4);
    (void)ws_size; // total ~33.6 MB
    // packed edge payload aliases h1+out1 (12.8 MB, consumed by passB before gemm1)
    unsigned* packed = (unsigned*)h1;

    const int gN4 = (N_NODES + 3) / 4;          // msg kernels: 4 nodes/block
    const int gN256 = (N_NODES + 255) / 256;
    const int gA = (E + TILE_A - 1) / TILE_A;

    k_zinit<<<(NBUCK + 255) / 256, 256, 0, stream>>>(bcount);
    k_bhist<<<512, 256, 0, stream>>>(dst, E, bcount);
    k_bscan<<<1, NBUCK, 0, stream>>>(bcount, bbase, cursor);
    k_passA<<<gA, 512, 0, stream>>>(src, dst, E, cursor, packed);
    k_passB<<<NBUCK, 256, 0, stream>>>(packed, bbase, sorted_src, offs, count, dinv);

    k_gemm1<<<(N_NODES + 127) / 128, 128, 0, stream>>>(x, W1, b1, dinv, h1, out1);
    k_msg1<<<gN4, 256, 0, stream>>>(offs, count, sorted_src, dinv, h1, out1);
    k_gemm2<<<gN256, 256, 0, stream>>>(out1, W2, b2, dinv, h2, out2);
    k_msg2<<<gN4, 256, 0, stream>>>(offs, count, sorted_src, dinv, h2, out2);
    k_logsm<<<gN256, 256, 0, stream>>>(out2, out);
}

// Round 4
// 496.403 us; speedup vs baseline: 1.7405x; 1.0887x over previous
//
#include <hip/hip_runtime.h>
#include <hip/hip_bf16.h>

// GCN 2-layer, N=100000, D=512->16->7, E=3.2M (+self loops), f32.
// Round 4: padded-bucket radix CSR (no global hist/scan); coalesced 4-lane-per-row
// gemm1 with LDS-swizzled W1; gemm2+relu fused into msg1; logsm+self fused into msg2.

#define N_NODES 100000
#define NPAD    100352
#define D_IN    512
#define H1DIM   16
#define C_PAD   8
#define NB      196      // nodes per bucket
#define NBUCK   512      // buckets
#define BCAP    8192     // padded per-bucket capacity (mean 6250, +24 sigma)
#define TILE_A  8192     // edges per pass-A workgroup

// ---------------- CSR build ----------------

__global__ __launch_bounds__(256) void k_initcur(int* __restrict__ cursor) {
    int i = blockIdx.x * 256 + threadIdx.x;
    if (i < NBUCK) cursor[i] = i * BCAP;
}

// partition edges into padded dst buckets; payload packs (dst_local<<17 | src)
__global__ __launch_bounds__(512) void k_passA(const int* __restrict__ src,
                                               const int* __restrict__ dst, int E,
                                               int* __restrict__ cursor,
                                               unsigned* __restrict__ packed) {
    __shared__ int hist[NBUCK];
    __shared__ int wp[NBUCK];
    int tile0 = blockIdx.x * TILE_A;
    for (int i = threadIdx.x; i < NBUCK; i += 512) hist[i] = 0;
    __syncthreads();
    unsigned pay[16];
    unsigned short bk[16];
#pragma unroll
    for (int r = 0; r < 16; ++r) {
        int e = tile0 + r * 512 + threadIdx.x;
        if (e < E) {
            unsigned d = (unsigned)dst[e];
            unsigned s = (unsigned)src[e];
            unsigned b = d / NB;
            pay[r] = ((d - b * NB) << 17) | s;
            bk[r] = (unsigned short)b;
            atomicAdd(&hist[b], 1);
        } else {
            bk[r] = 0xffffu;
        }
    }
    __syncthreads();
    {
        int c = hist[threadIdx.x];            // block=512=NBUCK
        wp[threadIdx.x] = c ? atomicAdd(&cursor[threadIdx.x], c) : 0;
    }
    __syncthreads();
#pragma unroll
    for (int r = 0; r < 16; ++r) {
        if (bk[r] != 0xffffu) {
            int pos = atomicAdd(&wp[bk[r]], 1);
            int lim = ((int)bk[r] + 1) * BCAP;
            if (pos < lim) packed[pos] = pay[r];   // overflow guard (never hit)
        }
    }
}

// one WG per bucket: LDS counting sort by dst_local; emit sorted_src (coalesced),
// per-node count/offs/dinv. offs = b*BCAP + local scan (padded CSR).
__global__ __launch_bounds__(256) void k_passB(const unsigned* __restrict__ packed,
                                               const int* __restrict__ cursor,
                                               int* __restrict__ sorted_src,
                                               int* __restrict__ offs,
                                               int* __restrict__ cnt_out,
                                               float* __restrict__ dinv) {
    __shared__ unsigned ent[BCAP];
    __shared__ int sorted[BCAP];
    __shared__ int hist[NB + 1];
    __shared__ int scan[NB + 1];
    __shared__ int wp[NB];
    int b = blockIdx.x;
    int base = b * BCAP;
    int cnt = cursor[b] - base;
    if (cnt > BCAP) cnt = BCAP;
    for (int i = threadIdx.x; i < cnt; i += 256) ent[i] = packed[base + i];
    for (int i = threadIdx.x; i <= NB; i += 256) hist[i] = 0;
    __syncthreads();
    for (int i = threadIdx.x; i < cnt; i += 256) atomicAdd(&hist[ent[i] >> 17], 1);
    __syncthreads();
    if (threadIdx.x <= NB)
        scan[threadIdx.x] = (threadIdx.x == 0) ? 0 : hist[threadIdx.x - 1];
    __syncthreads();
    for (int off = 1; off < 256; off <<= 1) {
        int v = 0;
        if (threadIdx.x <= NB && threadIdx.x >= off) v = scan[threadIdx.x - off];
        __syncthreads();
        if (threadIdx.x <= NB) scan[threadIdx.x] += v;
        __syncthreads();
    }
    int node0 = b * NB;
    if (threadIdx.x < NB) {
        int node = node0 + threadIdx.x;
        if (node < N_NODES) {
            int h = hist[threadIdx.x];
            cnt_out[node] = h;
            offs[node] = base + scan[threadIdx.x];
            dinv[node] = rsqrtf(1.0f + (float)h);
        }
        wp[threadIdx.x] = scan[threadIdx.x];
    }
    __syncthreads();
    for (int i = threadIdx.x; i < cnt; i += 256) {
        unsigned p = ent[i];
        int pos = atomicAdd(&wp[p >> 17], 1);
        sorted[pos] = (int)(p & 0x1FFFFu);
    }
    __syncthreads();
    for (int i = threadIdx.x; i < cnt; i += 256) sorted_src[base + i] = sorted[i];
}

// ---------------- layer math ----------------

// h1 = x @ W1. 4 lanes per row (sub=lane&3): contiguous 64B x-loads per row-quad,
// full line consumed per instruction. W1 in LDS, rotation-swizzled (q'=(q+d4)&3)
// so the 4 sub-lanes' ds_read_b128 hit disjoint bank quads.
__global__ __launch_bounds__(256) void k_gemm1(const float* __restrict__ x,
                                               const float4* __restrict__ W14,
                                               float* __restrict__ h1) {
    __shared__ float4 Wl[2048];            // 32 KB
    for (int g = threadIdx.x; g < 2048; g += 256) {
        int d = g >> 2, q = g & 3;
        Wl[d * 4 + ((q + (d >> 2)) & 3)] = W14[g];
    }
    int row = blockIdx.x * 64 + (threadIdx.x >> 2);
    int sub = threadIdx.x & 3;
    __syncthreads();
    if (row >= N_NODES) return;
    const float4* xr = (const float4*)(x + (size_t)row * D_IN);
    float acc[16];
#pragma unroll
    for (int k = 0; k < 16; ++k) acc[k] = 0.0f;

#pragma unroll 2
    for (int i = 0; i < 32; ++i) {
        int d4 = sub + i * 4;
        float4 xv = xr[d4];
        int rot = d4 & 3;                   // == sub, but keep general
#pragma unroll
        for (int r = 0; r < 4; ++r) {
            int d = d4 * 4 + r;
            float xs = (r == 0) ? xv.x : (r == 1) ? xv.y : (r == 2) ? xv.z : xv.w;
#pragma unroll
            for (int q = 0; q < 4; ++q) {
                float4 wv = Wl[d * 4 + ((q + rot) & 3)];
                acc[q * 4 + 0] = fmaf(xs, wv.x, acc[q * 4 + 0]);
                acc[q * 4 + 1] = fmaf(xs, wv.y, acc[q * 4 + 1]);
                acc[q * 4 + 2] = fmaf(xs, wv.z, acc[q * 4 + 2]);
                acc[q * 4 + 3] = fmaf(xs, wv.w, acc[q * 4 + 3]);
            }
        }
    }
#pragma unroll
    for (int k = 0; k < 16; ++k) {
        acc[k] += __shfl_xor(acc[k], 1);
        acc[k] += __shfl_xor(acc[k], 2);
    }
    float4 o;
    if (sub == 0)      o = make_float4(acc[0],  acc[1],  acc[2],  acc[3]);
    else if (sub == 1) o = make_float4(acc[4],  acc[5],  acc[6],  acc[7]);
    else if (sub == 2) o = make_float4(acc[8],  acc[9],  acc[10], acc[11]);
    else               o = make_float4(acc[12], acc[13], acc[14], acc[15]);
    ((float4*)(h1 + (size_t)row * H1DIM))[sub] = o;
}

// msg1 + self-loop + bias + relu + gemm2 fused. One wave per node.
// Phase 1: 4 edge slots x 16 features; phase 2: in-wave 16x7 matmul via shuffles.
__global__ __launch_bounds__(256) void k_msg1g2(const int* __restrict__ offs,
                                                const int* __restrict__ cnt_,
                                                const int* __restrict__ ssrc,
                                                const float* __restrict__ dinv,
                                                const float* __restrict__ h1,
                                                const float* __restrict__ b1,
                                                const float* __restrict__ W2,
                                                float* __restrict__ h2) {
    int node = blockIdx.x * 4 + (threadIdx.x >> 6);
    if (node >= N_NODES) return;
    int lane = threadIdx.x & 63;
    int s = lane >> 4;       // edge slot 0..3
    int k = lane & 15;       // feature
    int off = offs[node];
    int cnt = cnt_[node];
    float acc = 0.0f;
    for (int c = s; c < cnt; c += 4) {
        int sv = ssrc[off + c];
        acc = fmaf(dinv[sv], h1[(size_t)sv * H1DIM + k], acc);
    }
    acc += __shfl_xor(acc, 16);
    acc += __shfl_xor(acc, 32);             // every lane: full sum for its k
    float di = dinv[node];
    float v = fmaf(di, acc, fmaf(di * di, h1[(size_t)node * H1DIM + k], b1[k]));
    v = fmaxf(v, 0.0f);                     // relu
    // gemm2: lane = (kh, j); kh=lane>>3 sums k=kh and k=kh+8; reduce over kh
    int j = lane & 7, kh = lane >> 3;
    float t1 = __shfl(v, kh);
    float t2 = __shfl(v, kh + 8);
    float w1 = (j < 7) ? W2[kh * 7 + j] : 0.0f;
    float w2 = (j < 7) ? W2[(kh + 8) * 7 + j] : 0.0f;
    float p = t1 * w1 + t2 * w2;
    p += __shfl_xor(p, 8);
    p += __shfl_xor(p, 16);
    p += __shfl_xor(p, 32);                 // h2[j] complete at every lane
    if (lane < 8) h2[(size_t)node * C_PAD + j] = (j < 7) ? p : 0.0f;
}

// msg2 + self-loop + bias + log_softmax fused. One wave per node, 8 slots x 8 feat.
__global__ __launch_bounds__(256) void k_msg2sm(const int* __restrict__ offs,
                                                const int* __restrict__ cnt_,
                                                const int* __restrict__ ssrc,
                                                const float* __restrict__ dinv,
                                                const float* __restrict__ h2,
                                                const float* __restrict__ b2,
                                                float* __restrict__ out) {
    int node = blockIdx.x * 4 + (threadIdx.x >> 6);
    if (node >= N_NODES) return;
    int lane = threadIdx.x & 63;
    int s = lane >> 3;       // edge slot 0..7
    int j = lane & 7;        // feature (7 = pad)
    int off = offs[node];
    int cnt = cnt_[node];
    float acc = 0.0f;
    for (int c = s; c < cnt; c += 8) {
        int sv = ssrc[off + c];
        acc = fmaf(dinv[sv], h2[(size_t)sv * C_PAD + j], acc);
    }
    acc += __shfl_xor(acc, 8);
    acc += __shfl_xor(acc, 16);
    acc += __shfl_xor(acc, 32);             // every lane: full sum for its j
    float di = dinv[node];
    float v = (j < 7)
        ? fmaf(di, acc, fmaf(di * di, h2[(size_t)node * C_PAD + j], b2[j]))
        : -INFINITY;
    float m = v;
    m = fmaxf(m, __shfl_xor(m, 1));
    m = fmaxf(m, __shfl_xor(m, 2));
    m = fmaxf(m, __shfl_xor(m, 4));
    float e = expf(v - m);                  // j==7 -> 0
    float ss = e;
    ss += __shfl_xor(ss, 1);
    ss += __shfl_xor(ss, 2);
    ss += __shfl_xor(ss, 4);
    float r = v - m - logf(ss);
    if (s == 0 && j < 7) out[(size_t)node * 7 + j] = r;
}

// ---------------- launch ----------------

extern "C" void kernel_launch(void* const* d_in, const int* in_sizes, int n_in,
                              void* d_out, int out_size, void* d_ws, size_t ws_size,
                              hipStream_t stream) {
    const float* x  = (const float*)d_in[0];
    const int*   ei = (const int*)d_in[1];
    const float* W1 = (const float*)d_in[2];
    const float* b1 = (const float*)d_in[3];
    const float* W2 = (const float*)d_in[4];
    const float* b2 = (const float*)d_in[5];
    float* out = (float*)d_out;

    const int E = in_sizes[1] / 2;
    const int* src = ei;
    const int* dst = ei + E;

    char* w = (char*)d_ws;
    size_t off = 0;
    auto alloc = [&](size_t bytes) -> void* {
        off = (off + 255) & ~(size_t)255;
        void* p = w + off;
        off += bytes;
        return p;
    };
    int*      cursor     = (int*)alloc(NBUCK * 4);
    int*      count      = (int*)alloc(NPAD * 4);
    int*      offs       = (int*)alloc(NPAD * 4);
    float*    dinv       = (float*)alloc(NPAD * 4);
    unsigned* packed     = (unsigned*)alloc((size_t)NBUCK * BCAP * 4);  // 16.8 MB
    int*      sorted_src = (int*)alloc((size_t)NBUCK * BCAP * 4);       // 16.8 MB
    float*    h1         = (float*)alloc((size_t)N_NODES * H1DIM * 4);  // 6.4 MB
    float*    h2         = (float*)alloc((size_t)N_NODES * C_PAD * 4);  // 3.2 MB
    (void)ws_size; // ~44.6 MB

    const int gA = (E + TILE_A - 1) / TILE_A;
    const int gN4 = (N_NODES + 3) / 4;

    k_initcur<<<(NBUCK + 255) / 256, 256, 0, stream>>>(cursor);
    k_passA<<<gA, 512, 0, stream>>>(src, dst, E, cursor, packed);
    k_passB<<<NBUCK, 256, 0, stream>>>(packed, cursor, sorted_src, offs, count, dinv);

    k_gemm1<<<(N_NODES + 63) / 64, 256, 0, stream>>>(x, (const float4*)W1, h1);
    k_msg1g2<<<gN4, 256, 0, stream>>>(offs, count, sorted_src, dinv, h1, b1, W2, h2);
    k_msg2sm<<<gN4, 256, 0, stream>>>(offs, count, sorted_src, dinv, h2, b2, out);
}

// Round 5
// 440.095 us; speedup vs baseline: 1.9632x; 1.1279x over previous
//
#include <hip/hip_runtime.h>
#include <hip/hip_bf16.h>

// GCN 2-layer, N=100000, D=512->16->7, E=3.2M (+self loops), f32.
// Round 5: 4-aligned padded CSR segments -> int4 edge loads (4x ILP on the
// latency-bound gather chain); dinv folded into h1s/h2s tables (no per-edge
// dinv gather). CSR radix build and fused gemm2/logsm kept from round 4.

#define N_NODES 100000
#define NPAD    100352
#define D_IN    512
#define H1DIM   16
#define C_PAD   8
#define NB      196      // nodes per bucket
#define NBUCK   512      // buckets
#define BCAP    8192     // padded per-bucket capacity (mean 6250 + node pads)
#define TILE_A  8192     // edges per pass-A workgroup

// ---------------- CSR build ----------------

__global__ __launch_bounds__(256) void k_initcur(int* __restrict__ cursor) {
    int i = blockIdx.x * 256 + threadIdx.x;
    if (i < NBUCK) cursor[i] = i * BCAP;
}

// partition edges into padded dst buckets; payload packs (dst_local<<17 | src)
__global__ __launch_bounds__(512) void k_passA(const int* __restrict__ src,
                                               const int* __restrict__ dst, int E,
                                               int* __restrict__ cursor,
                                               unsigned* __restrict__ packed) {
    __shared__ int hist[NBUCK];
    __shared__ int wp[NBUCK];
    int tile0 = blockIdx.x * TILE_A;
    for (int i = threadIdx.x; i < NBUCK; i += 512) hist[i] = 0;
    __syncthreads();
    unsigned pay[16];
    unsigned short bk[16];
#pragma unroll
    for (int r = 0; r < 16; ++r) {
        int e = tile0 + r * 512 + threadIdx.x;
        if (e < E) {
            unsigned d = (unsigned)dst[e];
            unsigned s = (unsigned)src[e];
            unsigned b = d / NB;
            pay[r] = ((d - b * NB) << 17) | s;
            bk[r] = (unsigned short)b;
            atomicAdd(&hist[b], 1);
        } else {
            bk[r] = 0xffffu;
        }
    }
    __syncthreads();
    {
        int c = hist[threadIdx.x];            // block=512=NBUCK
        wp[threadIdx.x] = c ? atomicAdd(&cursor[threadIdx.x], c) : 0;
    }
    __syncthreads();
#pragma unroll
    for (int r = 0; r < 16; ++r) {
        if (bk[r] != 0xffffu) {
            int pos = atomicAdd(&wp[bk[r]], 1);
            int lim = ((int)bk[r] + 1) * BCAP;
            if (pos < lim) packed[pos] = pay[r];   // overflow guard (never hit)
        }
    }
}

// one WG per bucket: LDS counting sort by dst_local with per-node segments padded
// to multiples of 4 (int4-aligned for msg kernels); pad slots = sentinel node 0.
__global__ __launch_bounds__(256) void k_passB(const unsigned* __restrict__ packed,
                                               const int* __restrict__ cursor,
                                               int* __restrict__ sorted_src,
                                               int* __restrict__ offs,
                                               int* __restrict__ cnt_out,
                                               float* __restrict__ dinv) {
    __shared__ unsigned ent[BCAP];
    __shared__ int sorted[BCAP];
    __shared__ int hist[NB + 1];
    __shared__ int scanA[NB + 1];
    __shared__ int wp[NB];
    int b = blockIdx.x;
    int base = b * BCAP;
    int cnt = cursor[b] - base;
    if (cnt > BCAP) cnt = BCAP;
    for (int i = threadIdx.x; i < cnt; i += 256) ent[i] = packed[base + i];
    for (int i = threadIdx.x; i < BCAP; i += 256) sorted[i] = 0;  // sentinel pads
    for (int i = threadIdx.x; i <= NB; i += 256) hist[i] = 0;
    __syncthreads();
    for (int i = threadIdx.x; i < cnt; i += 256) atomicAdd(&hist[ent[i] >> 17], 1);
    __syncthreads();
    // exclusive scan of 4-aligned counts
    if (threadIdx.x <= NB)
        scanA[threadIdx.x] = (threadIdx.x == 0) ? 0 : ((hist[threadIdx.x - 1] + 3) & ~3);
    __syncthreads();
    for (int off = 1; off < 256; off <<= 1) {
        int v = 0;
        if (threadIdx.x <= NB && threadIdx.x >= off) v = scanA[threadIdx.x - off];
        __syncthreads();
        if (threadIdx.x <= NB) scanA[threadIdx.x] += v;
        __syncthreads();
    }
    int node0 = b * NB;
    if (threadIdx.x < NB) {
        int node = node0 + threadIdx.x;
        if (node < N_NODES) {
            int h = hist[threadIdx.x];
            cnt_out[node] = h;
            offs[node] = base + scanA[threadIdx.x];
            dinv[node] = rsqrtf(1.0f + (float)h);
        }
        wp[threadIdx.x] = scanA[threadIdx.x];
    }
    __syncthreads();
    for (int i = threadIdx.x; i < cnt; i += 256) {
        unsigned p = ent[i];
        int pos = atomicAdd(&wp[p >> 17], 1);
        sorted[pos] = (int)(p & 0x1FFFFu);
    }
    __syncthreads();
    int totA = scanA[NB];                     // aligned bucket total (<= BCAP)
    for (int i = threadIdx.x; i < totA; i += 256) sorted_src[base + i] = sorted[i];
}

// ---------------- layer math ----------------

// h1s = dinv * (x @ W1). 4 lanes per row, W1 LDS-swizzled (round 4 layout).
__global__ __launch_bounds__(256) void k_gemm1(const float* __restrict__ x,
                                               const float4* __restrict__ W14,
                                               const float* __restrict__ dinv,
                                               float* __restrict__ h1s) {
    __shared__ float4 Wl[2048];            // 32 KB
    for (int g = threadIdx.x; g < 2048; g += 256) {
        int d = g >> 2, q = g & 3;
        Wl[d * 4 + ((q + (d >> 2)) & 3)] = W14[g];
    }
    int row = blockIdx.x * 64 + (threadIdx.x >> 2);
    int sub = threadIdx.x & 3;
    __syncthreads();
    if (row >= N_NODES) return;
    const float4* xr = (const float4*)(x + (size_t)row * D_IN);
    float acc[16];
#pragma unroll
    for (int k = 0; k < 16; ++k) acc[k] = 0.0f;

#pragma unroll 2
    for (int i = 0; i < 32; ++i) {
        int d4 = sub + i * 4;
        float4 xv = xr[d4];
        int rot = d4 & 3;
#pragma unroll
        for (int r = 0; r < 4; ++r) {
            int d = d4 * 4 + r;
            float xs = (r == 0) ? xv.x : (r == 1) ? xv.y : (r == 2) ? xv.z : xv.w;
#pragma unroll
            for (int q = 0; q < 4; ++q) {
                float4 wv = Wl[d * 4 + ((q + rot) & 3)];
                acc[q * 4 + 0] = fmaf(xs, wv.x, acc[q * 4 + 0]);
                acc[q * 4 + 1] = fmaf(xs, wv.y, acc[q * 4 + 1]);
                acc[q * 4 + 2] = fmaf(xs, wv.z, acc[q * 4 + 2]);
                acc[q * 4 + 3] = fmaf(xs, wv.w, acc[q * 4 + 3]);
            }
        }
    }
#pragma unroll
    for (int k = 0; k < 16; ++k) {
        acc[k] += __shfl_xor(acc[k], 1);
        acc[k] += __shfl_xor(acc[k], 2);
    }
    float di = dinv[row];
    float4 o;
    if (sub == 0)      o = make_float4(acc[0],  acc[1],  acc[2],  acc[3]);
    else if (sub == 1) o = make_float4(acc[4],  acc[5],  acc[6],  acc[7]);
    else if (sub == 2) o = make_float4(acc[8],  acc[9],  acc[10], acc[11]);
    else               o = make_float4(acc[12], acc[13], acc[14], acc[15]);
    o.x *= di; o.y *= di; o.z *= di; o.w *= di;
    ((float4*)(h1s + (size_t)row * H1DIM))[sub] = o;
}

// msg1 + self + bias + relu + gemm2, writing h2s = dinv*h2. One wave per node.
// Edge loop: int4 src batch -> 4 independent gathers (latency hiding).
__global__ __launch_bounds__(256) void k_msg1g2(const int* __restrict__ offs,
                                                const int* __restrict__ cnt_,
                                                const int* __restrict__ ssrc,
                                                const float* __restrict__ dinv,
                                                const float* __restrict__ h1s,
                                                const float* __restrict__ b1,
                                                const float* __restrict__ W2,
                                                float* __restrict__ h2s) {
    int node = blockIdx.x * 4 + (threadIdx.x >> 6);
    if (node >= N_NODES) return;
    int lane = threadIdx.x & 63;
    int s = lane >> 4;       // edge quad 0..3
    int k = lane & 15;       // feature
    int off = offs[node];
    int cnt = cnt_[node];
    float acc = 0.0f;
    for (int c0 = s * 4; c0 < cnt; c0 += 16) {
        int4 sv = *(const int4*)(ssrc + off + c0);   // 16B-aligned (padded CSR)
        float g0 = h1s[(size_t)(unsigned)sv.x * H1DIM + k];
        float g1 = h1s[(size_t)(unsigned)sv.y * H1DIM + k];
        float g2 = h1s[(size_t)(unsigned)sv.z * H1DIM + k];
        float g3 = h1s[(size_t)(unsigned)sv.w * H1DIM + k];
        acc += g0;                                   // c0 < cnt by loop bound
        acc += (c0 + 1 < cnt) ? g1 : 0.0f;
        acc += (c0 + 2 < cnt) ? g2 : 0.0f;
        acc += (c0 + 3 < cnt) ? g3 : 0.0f;
    }
    acc += __shfl_xor(acc, 16);
    acc += __shfl_xor(acc, 32);             // full neighbor sum at every lane
    float di = dinv[node];
    float v = fmaf(di, acc + h1s[(size_t)node * H1DIM + k], b1[k]);
    v = fmaxf(v, 0.0f);                     // relu
    // gemm2: lane = (kh, j); kh sums features kh and kh+8; reduce over kh
    int j = lane & 7, kh = lane >> 3;
    float t1 = __shfl(v, kh);
    float t2 = __shfl(v, kh + 8);
    float w1 = (j < 7) ? W2[kh * 7 + j] : 0.0f;
    float w2 = (j < 7) ? W2[(kh + 8) * 7 + j] : 0.0f;
    float p = t1 * w1 + t2 * w2;
    p += __shfl_xor(p, 8);
    p += __shfl_xor(p, 16);
    p += __shfl_xor(p, 32);                 // h2[j] complete at every lane
    if (lane < 8) h2s[(size_t)node * C_PAD + j] = (j < 7) ? di * p : 0.0f;
}

// msg2 + self + bias + log_softmax. One wave per node, 8 quads x 8 features.
__global__ __launch_bounds__(256) void k_msg2sm(const int* __restrict__ offs,
                                                const int* __restrict__ cnt_,
                                                const int* __restrict__ ssrc,
                                                const float* __restrict__ dinv,
                                                const float* __restrict__ h2s,
                                                const float* __restrict__ b2,
                                                float* __restrict__ out) {
    int node = blockIdx.x * 4 + (threadIdx.x >> 6);
    if (node >= N_NODES) return;
    int lane = threadIdx.x & 63;
    int s = lane >> 3;       // edge quad 0..7
    int j = lane & 7;        // feature (7 = pad)
    int off = offs[node];
    int cnt = cnt_[node];
    float acc = 0.0f;
    for (int c0 = s * 4; c0 < cnt; c0 += 32) {
        int4 sv = *(const int4*)(ssrc + off + c0);
        float g0 = h2s[(size_t)(unsigned)sv.x * C_PAD + j];
        float g1 = h2s[(size_t)(unsigned)sv.y * C_PAD + j];
        float g2 = h2s[(size_t)(unsigned)sv.z * C_PAD + j];
        float g3 = h2s[(size_t)(unsigned)sv.w * C_PAD + j];
        acc += g0;
        acc += (c0 + 1 < cnt) ? g1 : 0.0f;
        acc += (c0 + 2 < cnt) ? g2 : 0.0f;
        acc += (c0 + 3 < cnt) ? g3 : 0.0f;
    }
    acc += __shfl_xor(acc, 8);
    acc += __shfl_xor(acc, 16);
    acc += __shfl_xor(acc, 32);             // full neighbor sum at every lane
    float di = dinv[node];
    float v = (j < 7)
        ? fmaf(di, acc + h2s[(size_t)node * C_PAD + j], b2[j])
        : -INFINITY;
    float m = v;
    m = fmaxf(m, __shfl_xor(m, 1));
    m = fmaxf(m, __shfl_xor(m, 2));
    m = fmaxf(m, __shfl_xor(m, 4));
    float e = expf(v - m);                  // j==7 -> 0
    float ss = e;
    ss += __shfl_xor(ss, 1);
    ss += __shfl_xor(ss, 2);
    ss += __shfl_xor(ss, 4);
    float r = v - m - logf(ss);
    if (s == 0 && j < 7) out[(size_t)node * 7 + j] = r;
}

// ---------------- launch ----------------

extern "C" void kernel_launch(void* const* d_in, const int* in_sizes, int n_in,
                              void* d_out, int out_size, void* d_ws, size_t ws_size,
                              hipStream_t stream) {
    const float* x  = (const float*)d_in[0];
    const int*   ei = (const int*)d_in[1];
    const float* W1 = (const float*)d_in[2];
    const float* b1 = (const float*)d_in[3];
    const float* W2 = (const float*)d_in[4];
    const float* b2 = (const float*)d_in[5];
    float* out = (float*)d_out;

    const int E = in_sizes[1] / 2;
    const int* src = ei;
    const int* dst = ei + E;

    char* w = (char*)d_ws;
    size_t off = 0;
    auto alloc = [&](size_t bytes) -> void* {
        off = (off + 255) & ~(size_t)255;
        void* p = w + off;
        off += bytes;
        return p;
    };
    int*      cursor     = (int*)alloc(NBUCK * 4);
    int*      count      = (int*)alloc(NPAD * 4);
    int*      offs       = (int*)alloc(NPAD * 4);
    float*    dinv       = (float*)alloc(NPAD * 4);
    float*    h2s        = (float*)alloc((size_t)N_NODES * C_PAD * 4);  // 3.2 MB
    float*    h1s        = (float*)alloc((size_t)N_NODES * H1DIM * 4);  // 6.4 MB
    unsigned* packed     = (unsigned*)alloc((size_t)NBUCK * BCAP * 4);  // 16.8 MB
    int*      sorted_src = (int*)alloc((size_t)NBUCK * BCAP * 4);       // 16.8 MB
    (void)ws_size; // ~44.6 MB

    const int gA = (E + TILE_A - 1) / TILE_A;
    const int gN4 = (N_NODES + 3) / 4;

    k_initcur<<<(NBUCK + 255) / 256, 256, 0, stream>>>(cursor);
    k_passA<<<gA, 512, 0, stream>>>(src, dst, E, cursor, packed);
    k_passB<<<NBUCK, 256, 0, stream>>>(packed, cursor, sorted_src, offs, count, dinv);

    k_gemm1<<<(N_NODES + 63) / 64, 256, 0, stream>>>(x, (const float4*)W1, dinv, h1s);
    k_msg1g2<<<gN4, 256, 0, stream>>>(offs, count, sorted_src, dinv, h1s, b1, W2, h2s);
    k_msg2sm<<<gN4, 256, 0, stream>>>(offs, count, sorted_src, dinv, h2s, b2, out);
}